// Round 1
// baseline (433.396 us; speedup 1.0000x reference)
//
#include <hip/hip_runtime.h>
#include <math.h>

#define ACT_SCALE_F (1.0f / 12.0f)

// softplus + sigmoid from one exp: t = e^{-|x|}
__device__ __forceinline__ void sp_sig(float x, float& sp, float& sig) {
    float t = __expf(-fabsf(x));
    float r = __builtin_amdgcn_rcpf(1.0f + t);
    sp = fmaxf(x, 0.0f) + __logf(1.0f + t);
    sig = (x >= 0.0f) ? r : t * r;
}

__device__ __forceinline__ float sp_only(float x) {
    float t = __expf(-fabsf(x));
    return fmaxf(x, 0.0f) + __logf(1.0f + t);
}

__device__ __forceinline__ float sig_only(float x) {
    float t = __expf(-fabsf(x));
    float r = __builtin_amdgcn_rcpf(1.0f + t);
    return (x >= 0.0f) ? r : t * r;
}

// ws layout (floats):
// [0..1023]    spA1 row-major   spA1[i*32+j] = softplus(A1[i][j])
// [1024..2047] spA1T            [j*32+i]
// [2048..3071] spA2 row-major
// [3072..4095] spA2T
// [4096..4127] spAout
// [4128..4129] grad_ref (Bo_w omitted on both sides -> cancels)

__global__ void prep_kernel(const float* __restrict__ Bf_w, const float* __restrict__ Bf_b,
                            const float* __restrict__ A1,
                            const float* __restrict__ B1_w, const float* __restrict__ B1_b,
                            const float* __restrict__ A2,
                            const float* __restrict__ B2_w, const float* __restrict__ B2_b,
                            const float* __restrict__ A_out,
                            float* __restrict__ ws)
{
    __shared__ float sA1[1024], sA2[1024], sAout[32];
    __shared__ float vbufA[32], vbufB[32];
    __shared__ float part0[32], part1[32];
    const int tid = threadIdx.x;  // 64 threads, 1 block

    for (int e = tid; e < 1024; e += 64) {
        float w1 = sp_only(A1[e]);
        float w2 = sp_only(A2[e]);
        sA1[e] = w1;
        sA2[e] = w2;
        ws[e] = w1;
        ws[1024 + (e & 31) * 32 + (e >> 5)] = w1;
        ws[2048 + e] = w2;
        ws[3072 + (e & 31) * 32 + (e >> 5)] = w2;
    }
    if (tid < 32) {
        float ao = sp_only(A_out[tid]);
        sAout[tid] = ao;
        ws[4096 + tid] = ao;
    }
    __syncthreads();

    // grad_ref at z0 = 0, lanes 0..31 cooperate through LDS
    const int i = tid;
    float su1 = 0.f, g1 = 0.f, sb1 = 0.f;
    if (tid < 32) {
        float h0;
        sp_sig(Bf_b[i], h0, su1);
        vbufA[i] = h0;
    }
    __syncthreads();
    if (tid < 32) {
        float a1 = 0.f;
        for (int j = 0; j < 32; ++j) a1 = fmaf(vbufA[j], sA1[i * 32 + j], a1);
        float s1, sa1; sp_sig(a1, s1, sa1);
        g1 = 2.0f * ACT_SCALE_F * s1 * sa1;
        float spb1; sp_sig(B1_b[i], spb1, sb1);
        vbufB[i] = fmaf(ACT_SCALE_F * s1, s1, spb1);   // z1
    }
    __syncthreads();
    if (tid < 32) {
        float a2 = 0.f;
        for (int j = 0; j < 32; ++j) a2 = fmaf(vbufB[j], sA2[i * 32 + j], a2);
        float s2, sa2; sp_sig(a2, s2, sa2);
        float g2 = 2.0f * ACT_SCALE_F * s2 * sa2;
        float sb2 = sig_only(B2_b[i]);
        float ao = sAout[i];
        part0[i] = ao * sb2 * B2_w[i * 2 + 0];
        part1[i] = ao * sb2 * B2_w[i * 2 + 1];
        vbufA[i] = ao * g2;   // v2
    }
    __syncthreads();
    if (tid < 32) {
        float dz1 = 0.f;
        for (int ii = 0; ii < 32; ++ii) dz1 = fmaf(vbufA[ii], sA2[ii * 32 + i], dz1);
        part0[i] += dz1 * sb1 * B1_w[i * 2 + 0];
        part1[i] += dz1 * sb1 * B1_w[i * 2 + 1];
        vbufB[i] = dz1 * g1;   // v1
    }
    __syncthreads();
    if (tid < 32) {
        float dh0 = 0.f;
        for (int ii = 0; ii < 32; ++ii) dh0 = fmaf(vbufB[ii], sA1[ii * 32 + i], dh0);
        part0[i] += dh0 * su1 * Bf_w[i * 2 + 0];
        part1[i] += dh0 * su1 * Bf_w[i * 2 + 1];
    }
    __syncthreads();
    if (tid == 0) {
        float r0 = 0.f, r1 = 0.f;
        for (int j = 0; j < 32; ++j) { r0 += part0[j]; r1 += part1[j]; }
        ws[4128] = r0;
        ws[4129] = r1;
    }
}

__global__ void __launch_bounds__(256) icnn_main(
    const float* __restrict__ eps,
    const float* __restrict__ Bf_w, const float* __restrict__ Bf_b,
    const float* __restrict__ B1_w, const float* __restrict__ B1_b,
    const float* __restrict__ B2_w, const float* __restrict__ B2_b,
    const float* __restrict__ ws,
    float* __restrict__ out, int n)
{
    __shared__ float vbuf[256 * 33];   // per-thread 32-vec, stride-33 swizzle
    const int tid = threadIdx.x;
    const int idx = blockIdx.x * 256 + tid;
    if (idx >= n) return;
    float* vb = &vbuf[tid * 33];

    const float e11 = eps[3 * idx + 0];
    const float e22 = eps[3 * idx + 1];
    const float e12 = eps[3 * idx + 2];
    const float I1 = e11 + e22;
    const float I2 = e11 * e11 + 2.f * e12 * e12 + e22 * e22;

    const float* __restrict__ spA1   = ws;
    const float* __restrict__ spA1T  = ws + 1024;
    const float* __restrict__ spA2   = ws + 2048;
    const float* __restrict__ spA2T  = ws + 3072;
    const float* __restrict__ spAout = ws + 4096;

    float su1[32], g1[32], sb1[32];
    float acc[32];

    // ---- layer 0: h0 = sp(z0 @ Bf_w.T + Bf_b) ----
    #pragma unroll
    for (int i = 0; i < 32; ++i) {
        float u1 = fmaf(I2, Bf_w[2 * i + 1], fmaf(I1, Bf_w[2 * i], Bf_b[i]));
        float h0;
        sp_sig(u1, h0, su1[i]);
        vb[i] = h0;
    }

    // ---- a1 = spA1 @ h0 (reduction rolled, weights via spA1T) ----
    #pragma unroll
    for (int o = 0; o < 32; ++o) acc[o] = 0.f;
    #pragma unroll 2
    for (int r = 0; r < 32; ++r) {
        const float v = vb[r];
        const float* __restrict__ w = spA1T + r * 32;
        #pragma unroll
        for (int o = 0; o < 32; ++o) acc[o] = fmaf(v, w[o], acc[o]);
    }

    // ---- layer 1 elementwise ----
    #pragma unroll
    for (int i = 0; i < 32; ++i) {
        float s1, sa1;
        sp_sig(acc[i], s1, sa1);
        g1[i] = (2.0f * ACT_SCALE_F) * s1 * sa1;
        float b1 = fmaf(I2, B1_w[2 * i + 1], fmaf(I1, B1_w[2 * i], B1_b[i]));
        float spb1;
        sp_sig(b1, spb1, sb1[i]);
        vb[i] = fmaf(ACT_SCALE_F * s1, s1, spb1);   // z1
    }

    // ---- a2 = spA2 @ z1 ----
    #pragma unroll
    for (int o = 0; o < 32; ++o) acc[o] = 0.f;
    #pragma unroll 2
    for (int r = 0; r < 32; ++r) {
        const float v = vb[r];
        const float* __restrict__ w = spA2T + r * 32;
        #pragma unroll
        for (int o = 0; o < 32; ++o) acc[o] = fmaf(v, w[o], acc[o]);
    }

    // ---- layer 2 elementwise + B2_w grad contribution + v2 ----
    float gx0 = 0.f, gx1 = 0.f;
    #pragma unroll
    for (int i = 0; i < 32; ++i) {
        float s2, sa2;
        sp_sig(acc[i], s2, sa2);
        float g2 = (2.0f * ACT_SCALE_F) * s2 * sa2;
        float b2 = fmaf(I2, B2_w[2 * i + 1], fmaf(I1, B2_w[2 * i], B2_b[i]));
        float sb2 = sig_only(b2);
        float ao = spAout[i];
        float t = ao * sb2;
        gx0 = fmaf(t, B2_w[2 * i], gx0);
        gx1 = fmaf(t, B2_w[2 * i + 1], gx1);
        vb[i] = ao * g2;   // v2
    }

    // ---- backward: dz1_j = sum_i v2_i * spA2[i][j] ----
    #pragma unroll
    for (int o = 0; o < 32; ++o) acc[o] = 0.f;
    #pragma unroll 2
    for (int r = 0; r < 32; ++r) {
        const float v = vb[r];
        const float* __restrict__ w = spA2 + r * 32;
        #pragma unroll
        for (int o = 0; o < 32; ++o) acc[o] = fmaf(v, w[o], acc[o]);
    }

    #pragma unroll
    for (int j = 0; j < 32; ++j) {
        float dz1 = acc[j];
        float t = dz1 * sb1[j];
        gx0 = fmaf(t, B1_w[2 * j], gx0);
        gx1 = fmaf(t, B1_w[2 * j + 1], gx1);
        vb[j] = dz1 * g1[j];   // v1
    }

    // ---- backward: dh0_j = sum_i v1_i * spA1[i][j] ----
    #pragma unroll
    for (int o = 0; o < 32; ++o) acc[o] = 0.f;
    #pragma unroll 2
    for (int r = 0; r < 32; ++r) {
        const float v = vb[r];
        const float* __restrict__ w = spA1 + r * 32;
        #pragma unroll
        for (int o = 0; o < 32; ++o) acc[o] = fmaf(v, w[o], acc[o]);
    }

    #pragma unroll
    for (int j = 0; j < 32; ++j) {
        float t = acc[j] * su1[j];
        gx0 = fmaf(t, Bf_w[2 * j], gx0);
        gx1 = fmaf(t, Bf_w[2 * j + 1], gx1);
    }

    const float dI1 = gx0 - ws[4128];
    const float dI2 = gx1 - ws[4129];
    out[3 * idx + 0] = fmaf(2.f * e11, dI2, dI1);
    out[3 * idx + 1] = fmaf(2.f * e22, dI2, dI1);
    out[3 * idx + 2] = 2.f * e12 * dI2;
}

extern "C" void kernel_launch(void* const* d_in, const int* in_sizes, int n_in,
                              void* d_out, int out_size, void* d_ws, size_t ws_size,
                              hipStream_t stream)
{
    const float* eps   = (const float*)d_in[0];
    const float* Bf_w  = (const float*)d_in[1];
    const float* Bf_b  = (const float*)d_in[2];
    const float* A1    = (const float*)d_in[3];
    const float* B1_w  = (const float*)d_in[4];
    const float* B1_b  = (const float*)d_in[5];
    const float* A2    = (const float*)d_in[6];
    const float* B2_w  = (const float*)d_in[7];
    const float* B2_b  = (const float*)d_in[8];
    const float* A_out = (const float*)d_in[9];
    // d_in[10] = Bo_w (cancels in grads - grad_ref), d_in[11] = Bo_b (no grad)

    float* ws  = (float*)d_ws;
    float* out = (float*)d_out;
    const int n = in_sizes[0] / 3;

    prep_kernel<<<1, 64, 0, stream>>>(Bf_w, Bf_b, A1, B1_w, B1_b, A2, B2_w, B2_b, A_out, ws);
    const int blocks = (n + 255) / 256;
    icnn_main<<<blocks, 256, 0, stream>>>(eps, Bf_w, Bf_b, B1_w, B1_b, B2_w, B2_b, ws, out, n);
}